// Round 11
// baseline (659.950 us; speedup 1.0000x reference)
//
#include <hip/hip_runtime.h>
#include <hip/hip_cooperative_groups.h>

namespace cg = cooperative_groups;

#define NN 100000
#define EE 640000
#define DD 128

typedef short bf16x8 __attribute__((ext_vector_type(8)));
typedef float f32x4 __attribute__((ext_vector_type(4)));

__device__ __forceinline__ unsigned short f2bf(float f) {
    union { float f; unsigned int u; } a; a.f = f;
    unsigned int u = a.u + 0x7fffu + ((a.u >> 16) & 1u);   // RNE
    return (unsigned short)(u >> 16);
}

__device__ __forceinline__ int wave_incl_scan(int v, int lane) {
#pragma unroll
    for (int d = 1; d < 64; d <<= 1) {
        int u = __shfl_up(v, d, 64);
        if (lane >= d) v += u;
    }
    return v;
}

// One cooperative kernel, 6 phases, 5 grid syncs. cnt[NN] doubles as the
// global range-allocator counter.
__global__ __launch_bounds__(256, 4) void k_mega(
    const float* __restrict__ x, const int* __restrict__ ei,
    const float* __restrict__ W1, const float* __restrict__ b1,
    const float* __restrict__ W2, const float* __restrict__ b2,
    float* __restrict__ out,
    unsigned short* __restrict__ xb, unsigned short* __restrict__ w1t,
    unsigned short* __restrict__ w2t, unsigned short* __restrict__ hb,
    int* __restrict__ cnt, int* __restrict__ offs, int* __restrict__ bucket)
{
    cg::grid_group grid = cg::this_grid();
    const int t = threadIdx.x;
    const int bid = blockIdx.x;
    const int nb = gridDim.x;
    const int gthreads = nb * 256;
    const int gt = bid * 256 + t;
    const int lane = t & 63, wv = t >> 6;

    __shared__ unsigned short lds[DD * DD];  // 32 KB (P5)
    __shared__ int wsum[4];                  // (P2)
    __shared__ int base;                     // (P2)

    // ---- P0: zero cnt[0..NN+3] (incl. allocator counter at cnt[NN]) ----
    for (int i = gt; i < (NN + 4) / 4; i += gthreads)
        reinterpret_cast<int4*>(cnt)[i] = make_int4(0, 0, 0, 0);
    grid.sync();

    // ---- P1: hist + x->bf16 + weight prep (mutually independent) ----
    for (int e = gt; e < EE; e += gthreads)
        atomicAdd(&cnt[ei[EE + e]], 1);
    for (int i = gt; i < NN * DD / 4; i += gthreads) {
        float4 v = *reinterpret_cast<const float4*>(x + (size_t)i * 4);
        unsigned int u0 = (unsigned)f2bf(v.x) | ((unsigned)f2bf(v.y) << 16);
        unsigned int u1 = (unsigned)f2bf(v.z) | ((unsigned)f2bf(v.w) << 16);
        *reinterpret_cast<uint2*>(xb + (size_t)i * 4) = make_uint2(u0, u1);
    }
    for (int idx = gt; idx < 2 * DD * DD; idx += gthreads) {
        const float* W = (idx < DD * DD) ? W1 : W2;
        unsigned short* O = (idx < DD * DD) ? w1t : w2t;
        int i = idx & (DD * DD - 1);
        int n = i >> 7, k = i & (DD - 1);
        O[i] = f2bf(W[k * DD + n]);          // O[n*128+k] = W[k][n]
    }
    grid.sync();

    // ---- P2: range allocator (offs[n]=start; cnt[n]=start as cursor) ----
    for (int tile = bid; tile < (NN + 255) / 256; tile += nb) {
        int i = tile * 256 + t;
        int v = (i < NN) ? cnt[i] : 0;
        int s = wave_incl_scan(v, lane);
        if (lane == 63) wsum[wv] = s;
        __syncthreads();
        if (t == 0)
            base = atomicAdd(&cnt[NN], wsum[0] + wsum[1] + wsum[2] + wsum[3]);
        __syncthreads();
        int off = base;
        for (int k = 0; k < wv; ++k) off += wsum[k];
        int start = off + s - v;
        if (i < NN) { offs[i] = start; cnt[i] = start; }
        __syncthreads();
    }
    grid.sync();

    // ---- P3: fill buckets ----
    for (int e = gt; e < EE; e += gthreads) {
        int r = ei[e];
        int c = ei[EE + e];
        bucket[atomicAdd(&cnt[c], 1)] = r;   // after fill, cnt[c] == range end
    }
    grid.sync();

    // ---- P4: gather, one node per wave, wave-stride ----
    {
        const unsigned int* xr = reinterpret_cast<const unsigned int*>(xb);
        unsigned int* hbw = reinterpret_cast<unsigned int*>(hb);
        int gw = bid * 4 + wv, nw = nb * 4;
        for (int n = gw; n < NN; n += nw) {
            unsigned int u = xr[(size_t)n * 64 + lane];
            float ax = __uint_as_float(u << 16);
            float ay = __uint_as_float(u & 0xffff0000u);
            int j = offs[n], je = cnt[n];
            for (; j + 7 < je; j += 8) {
                int a0 = bucket[j],     a1 = bucket[j + 1], a2 = bucket[j + 2], a3 = bucket[j + 3];
                int a4 = bucket[j + 4], a5 = bucket[j + 5], a6 = bucket[j + 6], a7 = bucket[j + 7];
                unsigned int u0 = xr[(size_t)a0 * 64 + lane];
                unsigned int u1 = xr[(size_t)a1 * 64 + lane];
                unsigned int u2 = xr[(size_t)a2 * 64 + lane];
                unsigned int u3 = xr[(size_t)a3 * 64 + lane];
                unsigned int u4 = xr[(size_t)a4 * 64 + lane];
                unsigned int u5 = xr[(size_t)a5 * 64 + lane];
                unsigned int u6 = xr[(size_t)a6 * 64 + lane];
                unsigned int u7 = xr[(size_t)a7 * 64 + lane];
                ax += __uint_as_float(u0 << 16) + __uint_as_float(u1 << 16)
                    + __uint_as_float(u2 << 16) + __uint_as_float(u3 << 16)
                    + __uint_as_float(u4 << 16) + __uint_as_float(u5 << 16)
                    + __uint_as_float(u6 << 16) + __uint_as_float(u7 << 16);
                ay += __uint_as_float(u0 & 0xffff0000u) + __uint_as_float(u1 & 0xffff0000u)
                    + __uint_as_float(u2 & 0xffff0000u) + __uint_as_float(u3 & 0xffff0000u)
                    + __uint_as_float(u4 & 0xffff0000u) + __uint_as_float(u5 & 0xffff0000u)
                    + __uint_as_float(u6 & 0xffff0000u) + __uint_as_float(u7 & 0xffff0000u);
            }
            if (j + 3 < je) {
                int a0 = bucket[j], a1 = bucket[j + 1], a2 = bucket[j + 2], a3 = bucket[j + 3];
                unsigned int u0 = xr[(size_t)a0 * 64 + lane];
                unsigned int u1 = xr[(size_t)a1 * 64 + lane];
                unsigned int u2 = xr[(size_t)a2 * 64 + lane];
                unsigned int u3 = xr[(size_t)a3 * 64 + lane];
                ax += __uint_as_float(u0 << 16) + __uint_as_float(u1 << 16)
                    + __uint_as_float(u2 << 16) + __uint_as_float(u3 << 16);
                ay += __uint_as_float(u0 & 0xffff0000u) + __uint_as_float(u1 & 0xffff0000u)
                    + __uint_as_float(u2 & 0xffff0000u) + __uint_as_float(u3 & 0xffff0000u);
                j += 4;
            }
            for (; j < je; ++j) {
                unsigned int uu = xr[(size_t)bucket[j] * 64 + lane];
                ax += __uint_as_float(uu << 16);
                ay += __uint_as_float(uu & 0xffff0000u);
            }
            hbw[(size_t)n * 64 + lane] = (unsigned)f2bf(ax) | ((unsigned)f2bf(ay) << 16);
        }
    }
    grid.sync();

    // ---- P5: MLP, one 128-row tile per block (tile-stride) ----
    {
        const int wr = wv >> 1, wc = wv & 1;
        const int hi = lane >> 4, lo = lane & 15;
        const f32x4 zero = {0.f, 0.f, 0.f, 0.f};
        const uint4* hrow = reinterpret_cast<const uint4*>(hb);

        for (int tile = bid; tile < (NN + 127) / 128; tile += nb) {
            const long base_row = (long)tile * 128;

            // stage bf16 h -> LDS (swizzled)
#pragma unroll
            for (int it = 0; it < 8; ++it) {
                int idx = it * 256 + t;
                int row = idx >> 4;
                long g = base_row + row;
                uint4 v = make_uint4(0u, 0u, 0u, 0u);
                if (g < NN) v = hrow[base_row * 16 + idx];
                int byte = (row * 256 + (idx & 15) * 16) ^ ((row & 7) << 4);
                *reinterpret_cast<uint4*>(reinterpret_cast<char*>(lds) + byte) = v;
            }
            __syncthreads();

            // GEMM1
            bf16x8 bw1[4][4];
#pragma unroll
            for (int n = 0; n < 4; ++n)
#pragma unroll
                for (int k = 0; k < 4; ++k)
                    bw1[n][k] = *reinterpret_cast<const bf16x8*>(
                        w1t + (wc * 64 + n * 16 + lo) * DD + k * 32 + hi * 8);

            f32x4 acc[4][4];
#pragma unroll
            for (int m = 0; m < 4; ++m)
#pragma unroll
                for (int n = 0; n < 4; ++n) acc[m][n] = zero;
#pragma unroll
            for (int m = 0; m < 4; ++m) {
                bf16x8 a[4];
                int r = wr * 64 + m * 16 + lo;
#pragma unroll
                for (int k = 0; k < 4; ++k) {
                    int byte = (r * 256 + k * 64 + hi * 16) ^ ((r & 7) << 4);
                    a[k] = *reinterpret_cast<const bf16x8*>(reinterpret_cast<const char*>(lds) + byte);
                }
#pragma unroll
                for (int n = 0; n < 4; ++n)
#pragma unroll
                    for (int k = 0; k < 4; ++k)
                        acc[m][n] = __builtin_amdgcn_mfma_f32_16x16x32_bf16(a[k], bw1[n][k], acc[m][n], 0, 0, 0);
            }
            __syncthreads();

            // epilogue 1: h1 = relu(acc+b1) -> LDS (swizzled)
            float bias1[4];
#pragma unroll
            for (int n = 0; n < 4; ++n) bias1[n] = b1[wc * 64 + n * 16 + lo];
#pragma unroll
            for (int m = 0; m < 4; ++m)
#pragma unroll
                for (int n = 0; n < 4; ++n)
#pragma unroll
                    for (int g = 0; g < 4; ++g) {
                        int row = wr * 64 + m * 16 + hi * 4 + g;
                        int col = wc * 64 + n * 16 + lo;
                        float v = fmaxf(acc[m][n][g] + bias1[n], 0.f);
                        int byte = (row * 256 + col * 2) ^ ((row & 7) << 4);
                        *reinterpret_cast<unsigned short*>(reinterpret_cast<char*>(lds) + byte) = f2bf(v);
                    }
            __syncthreads();

            // GEMM2
            bf16x8 bw2[4][4];
#pragma unroll
            for (int n = 0; n < 4; ++n)
#pragma unroll
                for (int k = 0; k < 4; ++k)
                    bw2[n][k] = *reinterpret_cast<const bf16x8*>(
                        w2t + (wc * 64 + n * 16 + lo) * DD + k * 32 + hi * 8);

            f32x4 acc2[4][4];
#pragma unroll
            for (int m = 0; m < 4; ++m)
#pragma unroll
                for (int n = 0; n < 4; ++n) acc2[m][n] = zero;
#pragma unroll
            for (int m = 0; m < 4; ++m) {
                bf16x8 a[4];
                int r = wr * 64 + m * 16 + lo;
#pragma unroll
                for (int k = 0; k < 4; ++k) {
                    int byte = (r * 256 + k * 64 + hi * 16) ^ ((r & 7) << 4);
                    a[k] = *reinterpret_cast<const bf16x8*>(reinterpret_cast<const char*>(lds) + byte);
                }
#pragma unroll
                for (int n = 0; n < 4; ++n)
#pragma unroll
                    for (int k = 0; k < 4; ++k)
                        acc2[m][n] = __builtin_amdgcn_mfma_f32_16x16x32_bf16(a[k], bw2[n][k], acc2[m][n], 0, 0, 0);
            }

            // store out = acc2 + b2 (f32)
            float bias2[4];
#pragma unroll
            for (int n = 0; n < 4; ++n) bias2[n] = b2[wc * 64 + n * 16 + lo];
#pragma unroll
            for (int m = 0; m < 4; ++m)
#pragma unroll
                for (int n = 0; n < 4; ++n)
#pragma unroll
                    for (int g = 0; g < 4; ++g) {
                        long row = base_row + wr * 64 + m * 16 + hi * 4 + g;
                        if (row < NN)
                            out[row * DD + wc * 64 + n * 16 + lo] = acc2[m][n][g] + bias2[n];
                    }
            __syncthreads();   // lds reuse across tile-stride iterations
        }
    }
}

extern "C" void kernel_launch(void* const* d_in, const int* in_sizes, int n_in,
                              void* d_out, int out_size, void* d_ws, size_t ws_size,
                              hipStream_t stream) {
    const float* x  = (const float*)d_in[0];
    const int*   ei = (const int*)d_in[1];
    const float* W1 = (const float*)d_in[2];
    const float* b1 = (const float*)d_in[3];
    const float* W2 = (const float*)d_in[4];
    const float* b2 = (const float*)d_in[5];
    float* out = (float*)d_out;

    char* ws = (char*)d_ws;
    unsigned short* xb  = (unsigned short*)ws;                 // 25,600,000 B
    unsigned short* w1t = (unsigned short*)(ws + 25600000);    // 32 KB
    unsigned short* w2t = w1t + DD * DD;                       // 32 KB
    unsigned short* hb  = (unsigned short*)(ws + 25665536);    // 25,600,000 B
    int* cnt    = (int*)(ws + 51265536);                       // NN+4 ints (cnt[NN]=alloc ctr)
    int* offs   = cnt + NN + 4;                                // NN ints (+pad)
    int* bucket = offs + NN + 4;                               // EE ints

    // co-resident grid: blocks/CU from occupancy query x CU count
    int occ = 0;
    hipOccupancyMaxActiveBlocksPerMultiprocessor(&occ, (const void*)k_mega, 256, 0);
    if (occ < 1) occ = 1;
    if (occ > 4) occ = 4;            // LDS allows 5; VGPR bound targets 4
    int dev = 0, cus = 0;
    hipGetDevice(&dev);
    hipDeviceGetAttribute(&cus, hipDeviceAttributeMultiprocessorCount, dev);
    if (cus <= 0) cus = 256;
    int grid = occ * cus;

    void* args[] = {(void*)&x, (void*)&ei, (void*)&W1, (void*)&b1, (void*)&W2, (void*)&b2,
                    (void*)&out, (void*)&xb, (void*)&w1t, (void*)&w2t, (void*)&hb,
                    (void*)&cnt, (void*)&offs, (void*)&bucket};
    hipLaunchCooperativeKernel((const void*)k_mega, dim3(grid), dim3(256), args, 0, stream);
}

// Round 14
// 226.316 us; speedup vs baseline: 2.9161x; 2.9161x over previous
//
#include <hip/hip_runtime.h>

#define NN 100000
#define EE 640000
#define DD 128

typedef short bf16x8 __attribute__((ext_vector_type(8)));
typedef float f32x4 __attribute__((ext_vector_type(4)));

__device__ __forceinline__ unsigned short f2bf(float f) {
    union { float f; unsigned int u; } a; a.f = f;
    unsigned int u = a.u + 0x7fffu + ((a.u >> 16) & 1u);   // RNE
    return (unsigned short)(u >> 16);
}

__device__ __forceinline__ int wave_incl_scan(int v, int lane) {
#pragma unroll
    for (int d = 1; d < 64; d <<= 1) {
        int u = __shfl_up(v, d, 64);
        if (lane >= d) v += u;
    }
    return v;
}

// ---- setup + hist in one kernel (cnt pre-zeroed by hipMemsetAsync).
//      hist records per-edge slot eslot[e] = old count (0..deg-1).
__global__ __launch_bounds__(256) void k_su_hist(const float* __restrict__ x,
                                                 const float* __restrict__ W1,
                                                 const float* __restrict__ W2,
                                                 const int* __restrict__ ei,
                                                 unsigned short* __restrict__ xb,
                                                 unsigned short* __restrict__ w1t,
                                                 unsigned short* __restrict__ w2t,
                                                 int* __restrict__ cnt,
                                                 int* __restrict__ eslot) {
    const int gt = blockIdx.x * 256 + threadIdx.x;
    const int gthreads = gridDim.x * 256;
    // x -> bf16 (3.2M uint2 chunks)
    for (int i = gt; i < NN * DD / 4; i += gthreads) {
        float4 v = *reinterpret_cast<const float4*>(x + (size_t)i * 4);
        unsigned int u0 = (unsigned)f2bf(v.x) | ((unsigned)f2bf(v.y) << 16);
        unsigned int u1 = (unsigned)f2bf(v.z) | ((unsigned)f2bf(v.w) << 16);
        *reinterpret_cast<uint2*>(xb + (size_t)i * 4) = make_uint2(u0, u1);
    }
    // W -> bf16 transposed
    for (int idx = gt; idx < 2 * DD * DD; idx += gthreads) {
        const float* W = (idx < DD * DD) ? W1 : W2;
        unsigned short* O = (idx < DD * DD) ? w1t : w2t;
        int i = idx & (DD * DD - 1);
        int n = i >> 7, k = i & (DD - 1);
        O[i] = f2bf(W[k * DD + n]);          // O[n*128+k] = W[k][n]
    }
    // hist + per-edge slot
    for (int e = gt; e < EE; e += gthreads) {
        int c = ei[EE + e];
        eslot[e] = atomicAdd(&cnt[c], 1);    // 0..deg-1
    }
}

// ---- range allocator: offs[i]=start; cnt[i]=start+deg (range end).
//      cnt[NN] (zeroed) is the global allocator counter.
__global__ __launch_bounds__(256) void k_offs(int* __restrict__ cnt,
                                              int* __restrict__ offs,
                                              int* __restrict__ gcount) {
    int t = threadIdx.x, lane = t & 63, wv = t >> 6;
    int i = blockIdx.x * 256 + t;
    int v = (i < NN) ? cnt[i] : 0;            // deg
    int s = wave_incl_scan(v, lane);
    __shared__ int wsum[4];
    __shared__ int base;
    if (lane == 63) wsum[wv] = s;
    __syncthreads();
    if (t == 0)
        base = atomicAdd(gcount, wsum[0] + wsum[1] + wsum[2] + wsum[3]);
    __syncthreads();
    int off = base;
    for (int k = 0; k < wv; ++k) off += wsum[k];
    int start = off + s - v;
    if (i < NN) { offs[i] = start; cnt[i] = start + v; }   // cnt = range end
}

// ---- fill: NO atomics — slot precomputed in hist ----
__global__ __launch_bounds__(256) void k_fill(const int* __restrict__ ei,
                                              const int* __restrict__ eslot,
                                              const int* __restrict__ offs,
                                              int* __restrict__ bucket) {
    int e = blockIdx.x * 256 + threadIdx.x;
    if (e >= EE) return;
    int r = ei[e];
    int c = ei[EE + e];
    bucket[offs[c] + eslot[e]] = r;
}

// ---- gather: hb[n] = bf16( x[n] + sum_{src->n} x[src] ), one node/wave ----
__global__ __launch_bounds__(256) void k_gather(const unsigned int* __restrict__ xr,
                                                const int* __restrict__ offs,
                                                const int* __restrict__ cnt,
                                                const int* __restrict__ bucket,
                                                unsigned int* __restrict__ hb) {
    int gid = blockIdx.x * 256 + threadIdx.x;
    int n = gid >> 6;
    if (n >= NN) return;
    int l = gid & 63;
    unsigned int u = xr[(size_t)n * 64 + l];      // self term (2 bf16)
    float ax = __uint_as_float(u << 16);
    float ay = __uint_as_float(u & 0xffff0000u);
    int j = offs[n], je = cnt[n];
    for (; j + 7 < je; j += 8) {
        int a0 = bucket[j],     a1 = bucket[j + 1], a2 = bucket[j + 2], a3 = bucket[j + 3];
        int a4 = bucket[j + 4], a5 = bucket[j + 5], a6 = bucket[j + 6], a7 = bucket[j + 7];
        unsigned int u0 = xr[(size_t)a0 * 64 + l];
        unsigned int u1 = xr[(size_t)a1 * 64 + l];
        unsigned int u2 = xr[(size_t)a2 * 64 + l];
        unsigned int u3 = xr[(size_t)a3 * 64 + l];
        unsigned int u4 = xr[(size_t)a4 * 64 + l];
        unsigned int u5 = xr[(size_t)a5 * 64 + l];
        unsigned int u6 = xr[(size_t)a6 * 64 + l];
        unsigned int u7 = xr[(size_t)a7 * 64 + l];
        ax += __uint_as_float(u0 << 16) + __uint_as_float(u1 << 16)
            + __uint_as_float(u2 << 16) + __uint_as_float(u3 << 16)
            + __uint_as_float(u4 << 16) + __uint_as_float(u5 << 16)
            + __uint_as_float(u6 << 16) + __uint_as_float(u7 << 16);
        ay += __uint_as_float(u0 & 0xffff0000u) + __uint_as_float(u1 & 0xffff0000u)
            + __uint_as_float(u2 & 0xffff0000u) + __uint_as_float(u3 & 0xffff0000u)
            + __uint_as_float(u4 & 0xffff0000u) + __uint_as_float(u5 & 0xffff0000u)
            + __uint_as_float(u6 & 0xffff0000u) + __uint_as_float(u7 & 0xffff0000u);
    }
    if (j + 3 < je) {
        int a0 = bucket[j], a1 = bucket[j + 1], a2 = bucket[j + 2], a3 = bucket[j + 3];
        unsigned int u0 = xr[(size_t)a0 * 64 + l];
        unsigned int u1 = xr[(size_t)a1 * 64 + l];
        unsigned int u2 = xr[(size_t)a2 * 64 + l];
        unsigned int u3 = xr[(size_t)a3 * 64 + l];
        ax += __uint_as_float(u0 << 16) + __uint_as_float(u1 << 16)
            + __uint_as_float(u2 << 16) + __uint_as_float(u3 << 16);
        ay += __uint_as_float(u0 & 0xffff0000u) + __uint_as_float(u1 & 0xffff0000u)
            + __uint_as_float(u2 & 0xffff0000u) + __uint_as_float(u3 & 0xffff0000u);
        j += 4;
    }
    for (; j < je; ++j) {
        unsigned int uu = xr[(size_t)bucket[j] * 64 + l];
        ax += __uint_as_float(uu << 16);
        ay += __uint_as_float(uu & 0xffff0000u);
    }
    hb[(size_t)n * 64 + l] = (unsigned)f2bf(ax) | ((unsigned)f2bf(ay) << 16);
}

// ---------------- fused MLP: out = relu(h@W1+b1)@W2 + b2 (h is bf16) ----------
__global__ __launch_bounds__(256, 2) void k_mlp(const unsigned short* __restrict__ hb,
                                                const unsigned short* __restrict__ w1t,
                                                const unsigned short* __restrict__ w2t,
                                                const float* __restrict__ b1,
                                                const float* __restrict__ b2,
                                                float* __restrict__ out) {
    __shared__ unsigned short lds[DD * DD];  // 32 KB, swizzled h tile
    const int t  = threadIdx.x;
    const int w  = t >> 6, l = t & 63;
    const int wr = w >> 1, wc = w & 1;
    const int hi = l >> 4, lo = l & 15;
    const long base_row = (long)blockIdx.x * 128;

    const uint4* hrow = reinterpret_cast<const uint4*>(hb);
#pragma unroll
    for (int it = 0; it < 8; ++it) {
        int idx = it * 256 + t;
        int row = idx >> 4;
        long g = base_row + row;
        uint4 v = make_uint4(0u, 0u, 0u, 0u);
        if (g < NN) v = hrow[base_row * 16 + idx];
        int byte = (row * 256 + (idx & 15) * 16) ^ ((row & 7) << 4);
        *reinterpret_cast<uint4*>(reinterpret_cast<char*>(lds) + byte) = v;
    }
    __syncthreads();

    const f32x4 zero = {0.f, 0.f, 0.f, 0.f};

    bf16x8 bw1[4][4];
#pragma unroll
    for (int n = 0; n < 4; ++n)
#pragma unroll
        for (int k = 0; k < 4; ++k)
            bw1[n][k] = *reinterpret_cast<const bf16x8*>(
                w1t + (wc * 64 + n * 16 + lo) * DD + k * 32 + hi * 8);

    f32x4 acc[4][4];
#pragma unroll
    for (int m = 0; m < 4; ++m)
#pragma unroll
        for (int n = 0; n < 4; ++n) acc[m][n] = zero;
#pragma unroll
    for (int m = 0; m < 4; ++m) {
        bf16x8 a[4];
        int r = wr * 64 + m * 16 + lo;
#pragma unroll
        for (int k = 0; k < 4; ++k) {
            int byte = (r * 256 + k * 64 + hi * 16) ^ ((r & 7) << 4);
            a[k] = *reinterpret_cast<const bf16x8*>(reinterpret_cast<const char*>(lds) + byte);
        }
#pragma unroll
        for (int n = 0; n < 4; ++n)
#pragma unroll
            for (int k = 0; k < 4; ++k)
                acc[m][n] = __builtin_amdgcn_mfma_f32_16x16x32_bf16(a[k], bw1[n][k], acc[m][n], 0, 0, 0);
    }
    __syncthreads();

    float bias1[4];
#pragma unroll
    for (int n = 0; n < 4; ++n) bias1[n] = b1[wc * 64 + n * 16 + lo];
#pragma unroll
    for (int m = 0; m < 4; ++m)
#pragma unroll
        for (int n = 0; n < 4; ++n)
#pragma unroll
            for (int g = 0; g < 4; ++g) {
                int row = wr * 64 + m * 16 + hi * 4 + g;
                int col = wc * 64 + n * 16 + lo;
                float v = fmaxf(acc[m][n][g] + bias1[n], 0.f);
                int byte = (row * 256 + col * 2) ^ ((row & 7) << 4);
                *reinterpret_cast<unsigned short*>(reinterpret_cast<char*>(lds) + byte) = f2bf(v);
            }
    __syncthreads();

    bf16x8 bw2[4][4];
#pragma unroll
    for (int n = 0; n < 4; ++n)
#pragma unroll
        for (int k = 0; k < 4; ++k)
            bw2[n][k] = *reinterpret_cast<const bf16x8*>(
                w2t + (wc * 64 + n * 16 + lo) * DD + k * 32 + hi * 8);

    f32x4 acc2[4][4];
#pragma unroll
    for (int m = 0; m < 4; ++m)
#pragma unroll
        for (int n = 0; n < 4; ++n) acc2[m][n] = zero;
#pragma unroll
    for (int m = 0; m < 4; ++m) {
        bf16x8 a[4];
        int r = wr * 64 + m * 16 + lo;
#pragma unroll
        for (int k = 0; k < 4; ++k) {
            int byte = (r * 256 + k * 64 + hi * 16) ^ ((r & 7) << 4);
            a[k] = *reinterpret_cast<const bf16x8*>(reinterpret_cast<const char*>(lds) + byte);
        }
#pragma unroll
        for (int n = 0; n < 4; ++n)
#pragma unroll
            for (int k = 0; k < 4; ++k)
                acc2[m][n] = __builtin_amdgcn_mfma_f32_16x16x32_bf16(a[k], bw2[n][k], acc2[m][n], 0, 0, 0);
    }

    float bias2[4];
#pragma unroll
    for (int n = 0; n < 4; ++n) bias2[n] = b2[wc * 64 + n * 16 + lo];
#pragma unroll
    for (int m = 0; m < 4; ++m)
#pragma unroll
        for (int n = 0; n < 4; ++n)
#pragma unroll
            for (int g = 0; g < 4; ++g) {
                long row = base_row + wr * 64 + m * 16 + hi * 4 + g;
                if (row < NN)
                    out[row * DD + wc * 64 + n * 16 + lo] = acc2[m][n][g] + bias2[n];
            }
}

extern "C" void kernel_launch(void* const* d_in, const int* in_sizes, int n_in,
                              void* d_out, int out_size, void* d_ws, size_t ws_size,
                              hipStream_t stream) {
    const float* x  = (const float*)d_in[0];
    const int*   ei = (const int*)d_in[1];
    const float* W1 = (const float*)d_in[2];
    const float* b1 = (const float*)d_in[3];
    const float* W2 = (const float*)d_in[4];
    const float* b2 = (const float*)d_in[5];
    float* out = (float*)d_out;

    char* ws = (char*)d_ws;
    unsigned short* xb  = (unsigned short*)ws;                 // 25,600,000 B
    unsigned short* w1t = (unsigned short*)(ws + 25600000);    // 32 KB
    unsigned short* w2t = w1t + DD * DD;                       // 32 KB
    unsigned short* hb  = (unsigned short*)(ws + 25665536);    // 25,600,000 B
    int* cnt    = (int*)(ws + 51265536);                       // NN+4 ints (cnt[NN]=alloc ctr)
    int* offs   = cnt + NN + 4;                                // NN ints (+pad)
    int* eslot  = offs + NN + 4;                               // EE ints
    int* bucket = eslot + EE;                                  // EE ints

    hipMemsetAsync(cnt, 0, (NN + 4) * sizeof(int), stream);    // zero cnt + alloc ctr
    k_su_hist<<<3200, 256, 0, stream>>>(x, W1, W2, ei, xb, w1t, w2t, cnt, eslot);
    k_offs<<<(NN + 255) / 256, 256, 0, stream>>>(cnt, offs, cnt + NN);
    k_fill<<<(EE + 255) / 256, 256, 0, stream>>>(ei, eslot, offs, bucket);
    k_gather<<<(NN * 64 + 255) / 256, 256, 0, stream>>>(
        (const unsigned int*)xb, offs, cnt, bucket, (unsigned int*)hb);
    k_mlp<<<(NN + 127) / 128, 256, 0, stream>>>(hb, w1t, w2t, b1, b2, out);
}